// Round 10
// baseline (207.003 us; speedup 1.0000x reference)
//
#include <hip/hip_runtime.h>
#include <stdint.h>

typedef __attribute__((ext_vector_type(8))) short bf16x8;
typedef __attribute__((ext_vector_type(4))) float f32x4;

__device__ __forceinline__ unsigned short bf16_of(float f) {
  union { float f; uint32_t u; } x; x.f = f;
  uint32_t r = x.u + 0x7fffu + ((x.u >> 16) & 1u);
  return (unsigned short)(r >> 16);
}

#define GLD16(gp, lp) __builtin_amdgcn_global_load_lds( \
    (const __attribute__((address_space(1))) uint32_t*)(gp), \
    (__attribute__((address_space(3))) uint32_t*)(lp), 16, 0, 0)

#define BAR() do { asm volatile("" ::: "memory"); __builtin_amdgcn_s_barrier(); asm volatile("" ::: "memory"); } while (0)

// ---------------- f32 -> bf16 convert (vectorized) ----------------
__global__ void cvt_f32_bf16(const float* __restrict__ src,
                             unsigned short* __restrict__ dst, int n4) {
  int i = blockIdx.x * blockDim.x + threadIdx.x;
  int stride = gridDim.x * blockDim.x;
  for (int j = i; j < n4; j += stride) {
    float4 f = ((const float4*)src)[j];
    union { unsigned short s[4]; uint2 v; } u;
    u.s[0] = bf16_of(f.x); u.s[1] = bf16_of(f.y);
    u.s[2] = bf16_of(f.z); u.s[3] = bf16_of(f.w);
    ((uint2*)dst)[j] = u.v;
  }
}

// ---- 128x128 GEMM, r6 free-run chassis, 64KB LDS -> 2 blocks/CU ----
// 4 waves (2x2), wave tile 64x64, BK=64, 2x32KB dbuf, stage 1 tile ahead
// (opposite parity). Per K-tile: vmcnt(0)+BAR at top (loads issued a full
// tile ago), 16 ds_reads + 8 stage GLD16, 32 MFMA (kk-outer, dep dist 16).
// Two INDEPENDENT blocks per CU drift out of phase -> one block's read burst
// overlaps the other's MFMA burst (the TLP r6's single block can't have).
// Decode: XCD c owns B-column group [c*GW, (c+1)*GW) -> B panel L2-resident.
template<int BIAS, int OUTF32, int GW>
__global__ __launch_bounds__(256, 2)
void gemm128(const unsigned short* __restrict__ A,
             const unsigned short* __restrict__ B,
             void* __restrict__ C, const float* __restrict__ bias,
             int N, int K)
{
  __shared__ __align__(1024) unsigned short sm[32768];  // 64 KB
  char* const smb = (char*)sm;
  const int tid = threadIdx.x, w = tid >> 6, lane = tid & 63;
  const int wm = w >> 1, wn = w & 1;
  const int fr = lane & 15, kg = lane >> 4;
  const int swz = (fr & 7) << 4;
  const int srow = lane >> 3, sslot = lane & 7;
  const int cXcd = blockIdx.x & 7, iIdx = blockIdx.x >> 3;
  const int mt = iIdx / GW, nt = cXcd * GW + iIdx % GW;
  const int NT = K >> 6;

  // per-thread constant staging offsets (elements), i = chunk group 0..3
  int stOff[4];
  #pragma unroll
  for (int i = 0; i < 4; ++i)
    stOff[i] = ((i * 4 + w) * 8 + srow) * K + (sslot ^ srow) * 8;

  const unsigned short* aBase = A + ((size_t)mt << 7) * K;
  const unsigned short* bBase = B + ((size_t)nt << 7) * K;

  auto STAGE = [&](const unsigned short* src, int opnd, int parity) {
    char* region = smb + opnd * 32768 + parity * 16384;
    #pragma unroll
    for (int i = 0; i < 4; ++i)
      GLD16(src + stOff[i], region + (i * 4 + w) * 1024);
  };
  auto LDA = [&](char* Ab, int m, int kk) -> bf16x8 {
    const int r = wm * 64 + m * 16 + fr;
    return *(const bf16x8*)(Ab + r * 128 + ((kk * 64 + kg * 16) ^ ((r & 7) << 4)));
  };
  auto LDB = [&](char* Bb, int n, int kk) -> bf16x8 {
    const int r = wn * 64 + n * 16 + fr;
    return *(const bf16x8*)(Bb + r * 128 + ((kk * 64 + kg * 16) ^ ((r & 7) << 4)));
  };

  f32x4 acc[4][4] = {};

  // prologue: stage tile 0 into parity 0
  STAGE(bBase, 1, 0);
  STAGE(aBase, 0, 0);

  for (int t = 0; t < NT; ++t) {
    char* Ab = smb + (t & 1) * 16384;
    char* Bb = smb + 32768 + (t & 1) * 16384;

    // single sync point: tile t fully landed; t-1 reads all consumed
    asm volatile("s_waitcnt vmcnt(0)" ::: "memory");
    BAR();

    bf16x8 a[4][2], bb[4][2];
    #pragma unroll
    for (int n = 0; n < 4; ++n) { bb[n][0] = LDB(Bb, n, 0); bb[n][1] = LDB(Bb, n, 1); }
    #pragma unroll
    for (int m = 0; m < 4; ++m) { a[m][0] = LDA(Ab, m, 0); a[m][1] = LDA(Ab, m, 1); }

    if (t + 1 < NT) {
      const int p1 = (t + 1) & 1;
      STAGE(bBase + ((t + 1) << 6), 1, p1);
      STAGE(aBase + ((t + 1) << 6), 0, p1);
    }

    __builtin_amdgcn_s_setprio(1);
    #pragma unroll
    for (int kk = 0; kk < 2; ++kk)
      #pragma unroll
      for (int m = 0; m < 4; ++m)
        #pragma unroll
        for (int n = 0; n < 4; ++n)
          acc[m][n] = __builtin_amdgcn_mfma_f32_16x16x32_bf16(a[m][kk], bb[n][kk], acc[m][n], 0, 0, 0);
    __builtin_amdgcn_s_setprio(0);
  }

  // epilogue: C/D layout col = lane&15, row = (lane>>4)*4 + reg
  const int bm0 = mt << 7, bn0 = nt << 7;
  #pragma unroll
  for (int n = 0; n < 4; ++n) {
    const int col = bn0 + wn * 64 + n * 16 + fr;
    float bb2 = 0.0f;
    if (BIAS && OUTF32) bb2 = bias[col];
    #pragma unroll
    for (int m = 0; m < 4; ++m) {
      const int row0 = bm0 + wm * 64 + m * 16 + kg * 4;
      #pragma unroll
      for (int rr = 0; rr < 4; ++rr) {
        if (OUTF32)
          ((float*)C)[(size_t)(row0 + rr) * N + col] = acc[m][n][rr] + bb2;
        else
          ((unsigned short*)C)[(size_t)(row0 + rr) * N + col] = bf16_of(acc[m][n][rr]);
      }
    }
  }
}

// ---------------- block-local attention: one (b,h,g) 64x64 block per WG ----
__global__ __launch_bounds__(256, 2)
void attn_block(const unsigned short* __restrict__ qkv,
                unsigned short* __restrict__ o)
{
  __shared__ __align__(1024) unsigned short Qs[64 * 64];
  __shared__ __align__(1024) unsigned short Ks[64 * 64];
  __shared__ __align__(1024) unsigned short Vt[64 * 64];
  __shared__ __align__(1024) unsigned short Ps[64 * 64];
  __shared__ __align__(1024) unsigned short Os[64 * 64];
  const int tid = threadIdx.x, w = tid >> 6, lane = tid & 63;
  const int g = blockIdx.x, h = blockIdx.y, b = blockIdx.z;
  const size_t mbase = (size_t)b * 4096 + (size_t)g * 64;
  const unsigned short* qg = qkv + mbase * 3072 + h * 64;
  const unsigned short* kgl = qkv + mbase * 3072 + 1024 + h * 64;
  const unsigned short* vg = qkv + mbase * 3072 + 2048 + h * 64;

  #pragma unroll
  for (int i = 0; i < 2; ++i) {
    const int chunk = i * 4 + w;
    const int row = chunk * 8 + (lane >> 3);
    const int c8 = (lane & 7) ^ (row & 7);
    GLD16(qg + (size_t)row * 3072 + c8 * 8, (char*)Qs + chunk * 1024);
    GLD16(kgl + (size_t)row * 3072 + c8 * 8, (char*)Ks + chunk * 1024);
  }
  #pragma unroll
  for (int i = 0; i < 2; ++i) {
    const int c = i * 256 + tid;
    const int n = c >> 3, d0 = (c & 7) * 8;
    bf16x8 v = *(const bf16x8*)(vg + (size_t)n * 3072 + d0);
    #pragma unroll
    for (int j = 0; j < 8; ++j) {
      const int d = d0 + j;
      const int bo = d * 128 + n * 2;
      *(unsigned short*)((char*)Vt + (bo ^ ((d & 7) << 4))) = (unsigned short)v[j];
    }
  }
  __syncthreads();

  const int fr = lane & 15, kg = lane >> 4;
  f32x4 s[4] = {};
  #pragma unroll
  for (int kt = 0; kt < 2; ++kt) {
    const int kb = kt * 64 + kg * 16;
    const int rq = w * 16 + fr;
    bf16x8 aq = *(const bf16x8*)((const char*)Qs + rq * 128 + (kb ^ ((rq & 7) << 4)));
    #pragma unroll
    for (int nf = 0; nf < 4; ++nf) {
      const int rk = nf * 16 + fr;
      bf16x8 bk = *(const bf16x8*)((const char*)Ks + rk * 128 + (kb ^ ((rk & 7) << 4)));
      s[nf] = __builtin_amdgcn_mfma_f32_16x16x32_bf16(aq, bk, s[nf], 0, 0, 0);
    }
  }

  const float scale = 0.125f;
  float inv[4];
  #pragma unroll
  for (int r = 0; r < 4; ++r) {
    float m0 = fmaxf(fmaxf(s[0][r], s[1][r]), fmaxf(s[2][r], s[3][r]));
    #pragma unroll
    for (int d = 1; d < 16; d <<= 1) m0 = fmaxf(m0, __shfl_xor(m0, d));
    float sum = 0.0f;
    #pragma unroll
    for (int nf = 0; nf < 4; ++nf) {
      float p = __expf((s[nf][r] - m0) * scale);
      s[nf][r] = p;
      sum += p;
    }
    #pragma unroll
    for (int d = 1; d < 16; d <<= 1) sum += __shfl_xor(sum, d);
    inv[r] = 1.0f / sum;
  }

  #pragma unroll
  for (int r = 0; r < 4; ++r) {
    const int m = w * 16 + kg * 4 + r;
    #pragma unroll
    for (int nf = 0; nf < 4; ++nf) {
      const int bo = m * 128 + (nf * 16 + fr) * 2;
      *(unsigned short*)((char*)Ps + (bo ^ ((m & 7) << 4))) = bf16_of(s[nf][r] * inv[r]);
    }
  }
  __syncthreads();

  f32x4 oa[4] = {};
  #pragma unroll
  for (int kt = 0; kt < 2; ++kt) {
    const int kb = kt * 64 + kg * 16;
    const int rp = w * 16 + fr;
    bf16x8 ap = *(const bf16x8*)((const char*)Ps + rp * 128 + (kb ^ ((rp & 7) << 4)));
    #pragma unroll
    for (int df = 0; df < 4; ++df) {
      const int rv = df * 16 + fr;
      bf16x8 bv = *(const bf16x8*)((const char*)Vt + rv * 128 + (kb ^ ((rv & 7) << 4)));
      oa[df] = __builtin_amdgcn_mfma_f32_16x16x32_bf16(ap, bv, oa[df], 0, 0, 0);
    }
  }

  // epilogue: swizzled LDS bounce -> coalesced 16B global stores
  #pragma unroll
  for (int df = 0; df < 4; ++df) {
    #pragma unroll
    for (int r = 0; r < 4; ++r) {
      const int m = w * 16 + kg * 4 + r;
      const int bo = m * 128 + (df * 16 + fr) * 2;
      *(unsigned short*)((char*)Os + (bo ^ ((m & 7) << 4))) = bf16_of(oa[df][r]);
    }
  }
  __syncthreads();
  {
    const int row = tid >> 2;
    const int sb = (tid & 3) * 32;
    const int sw = (row & 7) << 4;
    char* rp = (char*)Os + row * 128;
    uint4 v0 = *(uint4*)(rp + (sb ^ sw));
    uint4 v1 = *(uint4*)(rp + ((sb + 16) ^ sw));
    char* op = (char*)(o + (mbase + row) * 1024 + h * 64) + sb;
    *(uint4*)op = v0;
    *(uint4*)(op + 16) = v1;
  }
}

// ---------------- launch ----------------
extern "C" void kernel_launch(void* const* d_in, const int* in_sizes, int n_in,
                              void* d_out, int out_size, void* d_ws, size_t ws_size,
                              hipStream_t stream) {
  const float* x     = (const float*)d_in[0];
  const float* w_qkv = (const float*)d_in[1];
  const float* w_out = (const float*)d_in[2];
  const float* b_out = (const float*)d_in[3];
  char* ws = (char*)d_ws;
  const size_t SZ_X  = (size_t)16384 * 1024 * 2;
  const size_t SZ_WQ = (size_t)3072 * 1024 * 2;
  const size_t SZ_WO = (size_t)1024 * 1024 * 2;
  unsigned short* xb  = (unsigned short*)ws;
  unsigned short* wqb = (unsigned short*)(ws + SZ_X);
  unsigned short* wob = (unsigned short*)(ws + SZ_X + SZ_WQ);
  unsigned short* qkv = (unsigned short*)(ws + SZ_X + SZ_WQ + SZ_WO);
  unsigned short* ob  = xb;  // alias: x_bf16 dead after GEMM1

  cvt_f32_bf16<<<2048, 256, 0, stream>>>(x, xb, 16384 * 1024 / 4);
  cvt_f32_bf16<<<512, 256, 0, stream>>>(w_qkv, wqb, 3072 * 1024 / 4);
  cvt_f32_bf16<<<256, 256, 0, stream>>>(w_out, wob, 1024 * 1024 / 4);
  // qkv[16384,3072] = xb @ wqb^T  (3072 blocks; XCD-grouped, GW=3)
  gemm128<0,0,3><<<dim3(3072), 256, 0, stream>>>(xb, wqb, qkv, nullptr, 3072, 1024);
  // block-local attention -> ob[16384,1024]
  attn_block<<<dim3(64, 16, 4), 256, 0, stream>>>(qkv, ob);
  // out[16384,1024] = ob @ wob^T + b_out  (1024 blocks; GW=1)
  gemm128<1,1,1><<<dim3(1024), 256, 0, stream>>>(ob, wob, d_out, b_out, 1024, 1024);
}

// Round 11
// 173.366 us; speedup vs baseline: 1.1940x; 1.1940x over previous
//
#include <hip/hip_runtime.h>
#include <stdint.h>

typedef __attribute__((ext_vector_type(8))) short bf16x8;
typedef __attribute__((ext_vector_type(4))) float f32x4;

__device__ __forceinline__ unsigned short bf16_of(float f) {
  union { float f; uint32_t u; } x; x.f = f;
  uint32_t r = x.u + 0x7fffu + ((x.u >> 16) & 1u);
  return (unsigned short)(r >> 16);
}

#define GLD16(gp, lp) __builtin_amdgcn_global_load_lds( \
    (const __attribute__((address_space(1))) uint32_t*)(gp), \
    (__attribute__((address_space(3))) uint32_t*)(lp), 16, 0, 0)

#define BAR() do { asm volatile("" ::: "memory"); __builtin_amdgcn_s_barrier(); asm volatile("" ::: "memory"); } while (0)

// ---------------- fused f32 -> bf16 convert: x, w_qkv, w_out in one launch ----
__global__ void cvt_all(const float* __restrict__ x, const float* __restrict__ wq,
                        const float* __restrict__ wo,
                        unsigned short* __restrict__ xb, unsigned short* __restrict__ wqb,
                        unsigned short* __restrict__ wob) {
  const int N_X = 4194304, N_WQ = 786432, N_WO = 262144;  // float4 counts
  const int total = N_X + N_WQ + N_WO;
  int i = blockIdx.x * blockDim.x + threadIdx.x;
  int stride = gridDim.x * blockDim.x;
  for (int j = i; j < total; j += stride) {
    const float* src; unsigned short* dst; int off;
    if (j < N_X)            { src = x;  dst = xb;  off = j; }
    else if (j < N_X + N_WQ){ src = wq; dst = wqb; off = j - N_X; }
    else                    { src = wo; dst = wob; off = j - N_X - N_WQ; }
    float4 f = ((const float4*)src)[off];
    union { unsigned short s[4]; uint2 v; } u;
    u.s[0] = bf16_of(f.x); u.s[1] = bf16_of(f.y);
    u.s[2] = bf16_of(f.z); u.s[3] = bf16_of(f.w);
    ((uint2*)dst)[off] = u.v;
  }
}

// ---- persistent 256x256 GEMM, 1-barrier K-tile, 16x16x32 MFMA (r6 champion) ----
// 8 waves (2M x 4N), BK=64, 128KB LDS dbuf. Stage exactly 1 tile ahead into
// the opposite parity. Per K-tile: vmcnt(0)+barrier at top (waited loads were
// issued one full tile ago -> no stall; nothing younger in flight), then the
// whole tile free-runs: 16 ds_read (bb + a_lo) | 8 stage gloads | 32 MFMA |
// 8 ds_read (a_hi) | 32 MFMA. MFMA order kk-outer: dep distance 16.
template<int BIAS, int OUTF32, int GW, int NSEG>
__global__ __launch_bounds__(512, 2)
void gemm256h(const unsigned short* __restrict__ A,
              const unsigned short* __restrict__ B,
              void* __restrict__ C, const float* __restrict__ bias,
              int N, int K)
{
  __shared__ __align__(1024) unsigned short sm[65536];  // 128 KB
  char* const smb = (char*)sm;
  const int tid = threadIdx.x, w = tid >> 6, lane = tid & 63;
  const int wm = w >> 2, wn = w & 3;
  const int fr = lane & 15, kg = lane >> 4;
  const int swz = (fr & 7) << 4;
  const int srow = lane >> 3, sslot = lane & 7;
  const int cXcd = blockIdx.x & 7, iIdx = blockIdx.x >> 3;
  const int NT_tot = NSEG * 16;  // K=1024 per output tile

  auto tileMN = [&](int s, int& mt, int& nt) {
    const int T = cXcd * (32 * NSEG) + s * 32 + iIdx;
    const int g = T / (64 * GW), rr = T % (64 * GW);
    mt = rr / GW; nt = g * GW + rr % GW;
  };

  // per-thread constant staging offsets (elements): [half][i2]
  int stOff[2][2];
  #pragma unroll
  for (int h = 0; h < 2; ++h)
    #pragma unroll
    for (int i2 = 0; i2 < 2; ++i2)
      stOff[h][i2] = (h * 128 + (i2 * 8 + w) * 8 + srow) * K + (sslot ^ srow) * 8;

  // segment base pointers (tileMN div/mod once per segment)
  int curMt, curNt, nxtMt, nxtNt;
  tileMN(0, curMt, curNt);
  nxtMt = curMt; nxtNt = curNt;
  if (NSEG > 1) tileMN(1, nxtMt, nxtNt);
  const unsigned short* aSeg  = A + ((size_t)curMt << 8) * K;
  const unsigned short* bSeg  = B + ((size_t)curNt << 8) * K;
  const unsigned short* aSegN = A + ((size_t)nxtMt << 8) * K;
  const unsigned short* bSegN = B + ((size_t)nxtNt << 8) * K;

  auto STAGEh = [&](const unsigned short* src, int opnd, int half, int parity) {
    char* region = smb + opnd * 65536 + parity * 32768 + half * 16384;
    GLD16(src + stOff[half][0], region + w * 1024);
    GLD16(src + stOff[half][1], region + (8 + w) * 1024);
  };
  auto LDA = [&](char* Ab, int j, int kk) -> bf16x8 {
    const int r = 32 * j + 16 * wm + fr;
    return *(const bf16x8*)(Ab + r * 128 + ((kk * 64 + kg * 16) ^ swz));
  };
  auto LDB = [&](char* Bb, int l, int kk) -> bf16x8 {
    const int r = 64 * l + 16 * wn + fr;
    return *(const bf16x8*)(Bb + r * 128 + ((kk * 64 + kg * 16) ^ swz));
  };

  f32x4 acc[8][4] = {};

  // prologue: stage tile 0
  STAGEh(bSeg, 1, 0, 0);
  STAGEh(aSeg, 0, 0, 0);
  STAGEh(bSeg, 1, 1, 0);
  STAGEh(aSeg, 0, 1, 0);

  for (int s = 0; s < NSEG; ++s) {
    for (int tt = 0; tt < 16; ++tt) {
      const int T = s * 16 + tt;
      char* Ab = smb + (T & 1) * 32768;
      char* Bb = smb + 65536 + (T & 1) * 32768;

      // ---- single sync point: tile T fully landed; T-1 reads all consumed
      asm volatile("s_waitcnt vmcnt(0)" ::: "memory");
      BAR();

      bf16x8 a[4][2], bb[4][2];
      // ds_reads first (critical path), B then A-low
      #pragma unroll
      for (int l = 0; l < 4; ++l) { bb[l][0] = LDB(Bb, l, 0); bb[l][1] = LDB(Bb, l, 1); }
      #pragma unroll
      for (int j = 0; j < 4; ++j) { a[j][0] = LDA(Ab, j, 0); a[j][1] = LDA(Ab, j, 1); }

      // stage all of T+1 into opposite parity (full-tile latency cover)
      if (T + 1 < NT_tot) {
        const int p1 = (T + 1) & 1;
        const unsigned short *aS, *bS;
        if (tt < 15) { aS = aSeg + ((tt + 1) << 6); bS = bSeg + ((tt + 1) << 6); }
        else         { aS = aSegN;                  bS = bSegN; }
        STAGEh(bS, 1, 0, p1);
        STAGEh(aS, 0, 0, p1);
        STAGEh(bS, 1, 1, p1);
        STAGEh(aS, 0, 1, p1);
      }

      // ---- A-low x all B: 32 MFMA, dep distance 16
      __builtin_amdgcn_s_setprio(1);
      #pragma unroll
      for (int kk = 0; kk < 2; ++kk)
        #pragma unroll
        for (int j = 0; j < 4; ++j)
          #pragma unroll
          for (int l = 0; l < 4; ++l)
            acc[j][l] = __builtin_amdgcn_mfma_f32_16x16x32_bf16(a[j][kk], bb[l][kk], acc[j][l], 0, 0, 0);
      __builtin_amdgcn_s_setprio(0);

      // ---- A-high reads + 32 MFMA
      #pragma unroll
      for (int j = 0; j < 4; ++j) { a[j][0] = LDA(Ab, j + 4, 0); a[j][1] = LDA(Ab, j + 4, 1); }
      __builtin_amdgcn_s_setprio(1);
      #pragma unroll
      for (int kk = 0; kk < 2; ++kk)
        #pragma unroll
        for (int j = 0; j < 4; ++j)
          #pragma unroll
          for (int l = 0; l < 4; ++l)
            acc[j + 4][l] = __builtin_amdgcn_mfma_f32_16x16x32_bf16(a[j][kk], bb[l][kk], acc[j + 4][l], 0, 0, 0);
      __builtin_amdgcn_s_setprio(0);
    }

    // ---- segment epilogue: C/D layout col = lane&15, row = (lane>>4)*4 + reg
    const int bm0 = curMt << 8, bn0 = curNt << 8;
    #pragma unroll
    for (int l = 0; l < 4; ++l) {
      const int col = bn0 + 64 * l + 16 * wn + fr;
      float bb2 = 0.0f;
      if (BIAS && OUTF32) bb2 = bias[col];
      #pragma unroll
      for (int j = 0; j < 8; ++j) {
        const int row0 = bm0 + 32 * j + 16 * wm + kg * 4;
        #pragma unroll
        for (int rr = 0; rr < 4; ++rr) {
          if (OUTF32)
            ((float*)C)[(size_t)(row0 + rr) * N + col] = acc[j][l][rr] + bb2;
          else
            ((unsigned short*)C)[(size_t)(row0 + rr) * N + col] = bf16_of(acc[j][l][rr]);
        }
      }
    }
    #pragma unroll
    for (int j = 0; j < 8; ++j)
      #pragma unroll
      for (int l = 0; l < 4; ++l)
        acc[j][l] = f32x4{0.f, 0.f, 0.f, 0.f};

    // advance segment pointers
    curMt = nxtMt; curNt = nxtNt;
    aSeg = aSegN; bSeg = bSegN;
    if (s + 2 < NSEG) {
      tileMN(s + 2, nxtMt, nxtNt);
      aSegN = A + ((size_t)nxtMt << 8) * K;
      bSegN = B + ((size_t)nxtNt << 8) * K;
    }
  }
}

// ---------------- block-local attention: one (b,h,g) 64x64 block per WG ----
// 40KB LDS, launch_bounds(256,4) -> 4 blocks/CU (latency hiding via TLP).
__global__ __launch_bounds__(256, 4)
void attn_block(const unsigned short* __restrict__ qkv,
                unsigned short* __restrict__ o)
{
  __shared__ __align__(1024) unsigned short Qs[64 * 64];
  __shared__ __align__(1024) unsigned short Ks[64 * 64];
  __shared__ __align__(1024) unsigned short Vt[64 * 64];
  __shared__ __align__(1024) unsigned short Ps[64 * 64];
  __shared__ __align__(1024) unsigned short Os[64 * 64];
  const int tid = threadIdx.x, w = tid >> 6, lane = tid & 63;
  const int g = blockIdx.x, h = blockIdx.y, b = blockIdx.z;
  const size_t mbase = (size_t)b * 4096 + (size_t)g * 64;
  const unsigned short* qg = qkv + mbase * 3072 + h * 64;
  const unsigned short* kgl = qkv + mbase * 3072 + 1024 + h * 64;
  const unsigned short* vg = qkv + mbase * 3072 + 2048 + h * 64;

  #pragma unroll
  for (int i = 0; i < 2; ++i) {
    const int chunk = i * 4 + w;
    const int row = chunk * 8 + (lane >> 3);
    const int c8 = (lane & 7) ^ (row & 7);
    GLD16(qg + (size_t)row * 3072 + c8 * 8, (char*)Qs + chunk * 1024);
    GLD16(kgl + (size_t)row * 3072 + c8 * 8, (char*)Ks + chunk * 1024);
  }
  #pragma unroll
  for (int i = 0; i < 2; ++i) {
    const int c = i * 256 + tid;
    const int n = c >> 3, d0 = (c & 7) * 8;
    bf16x8 v = *(const bf16x8*)(vg + (size_t)n * 3072 + d0);
    #pragma unroll
    for (int j = 0; j < 8; ++j) {
      const int d = d0 + j;
      const int bo = d * 128 + n * 2;
      *(unsigned short*)((char*)Vt + (bo ^ ((d & 7) << 4))) = (unsigned short)v[j];
    }
  }
  __syncthreads();

  const int fr = lane & 15, kg = lane >> 4;
  f32x4 s[4] = {};
  #pragma unroll
  for (int kt = 0; kt < 2; ++kt) {
    const int kb = kt * 64 + kg * 16;
    const int rq = w * 16 + fr;
    bf16x8 aq = *(const bf16x8*)((const char*)Qs + rq * 128 + (kb ^ ((rq & 7) << 4)));
    #pragma unroll
    for (int nf = 0; nf < 4; ++nf) {
      const int rk = nf * 16 + fr;
      bf16x8 bk = *(const bf16x8*)((const char*)Ks + rk * 128 + (kb ^ ((rk & 7) << 4)));
      s[nf] = __builtin_amdgcn_mfma_f32_16x16x32_bf16(aq, bk, s[nf], 0, 0, 0);
    }
  }

  const float scale = 0.125f;
  float inv[4];
  #pragma unroll
  for (int r = 0; r < 4; ++r) {
    float m0 = fmaxf(fmaxf(s[0][r], s[1][r]), fmaxf(s[2][r], s[3][r]));
    #pragma unroll
    for (int d = 1; d < 16; d <<= 1) m0 = fmaxf(m0, __shfl_xor(m0, d));
    float sum = 0.0f;
    #pragma unroll
    for (int nf = 0; nf < 4; ++nf) {
      float p = __expf((s[nf][r] - m0) * scale);
      s[nf][r] = p;
      sum += p;
    }
    #pragma unroll
    for (int d = 1; d < 16; d <<= 1) sum += __shfl_xor(sum, d);
    inv[r] = 1.0f / sum;
  }

  #pragma unroll
  for (int r = 0; r < 4; ++r) {
    const int m = w * 16 + kg * 4 + r;
    #pragma unroll
    for (int nf = 0; nf < 4; ++nf) {
      const int bo = m * 128 + (nf * 16 + fr) * 2;
      *(unsigned short*)((char*)Ps + (bo ^ ((m & 7) << 4))) = bf16_of(s[nf][r] * inv[r]);
    }
  }
  __syncthreads();

  f32x4 oa[4] = {};
  #pragma unroll
  for (int kt = 0; kt < 2; ++kt) {
    const int kb = kt * 64 + kg * 16;
    const int rp = w * 16 + fr;
    bf16x8 ap = *(const bf16x8*)((const char*)Ps + rp * 128 + (kb ^ ((rp & 7) << 4)));
    #pragma unroll
    for (int df = 0; df < 4; ++df) {
      const int rv = df * 16 + fr;
      bf16x8 bv = *(const bf16x8*)((const char*)Vt + rv * 128 + (kb ^ ((rv & 7) << 4)));
      oa[df] = __builtin_amdgcn_mfma_f32_16x16x32_bf16(ap, bv, oa[df], 0, 0, 0);
    }
  }

  // epilogue: swizzled LDS bounce -> coalesced 16B global stores
  #pragma unroll
  for (int df = 0; df < 4; ++df) {
    #pragma unroll
    for (int r = 0; r < 4; ++r) {
      const int m = w * 16 + kg * 4 + r;
      const int bo = m * 128 + (df * 16 + fr) * 2;
      *(unsigned short*)((char*)Os + (bo ^ ((m & 7) << 4))) = bf16_of(oa[df][r]);
    }
  }
  __syncthreads();
  {
    const int row = tid >> 2;
    const int sb = (tid & 3) * 32;
    const int sw = (row & 7) << 4;
    char* rp = (char*)Os + row * 128;
    uint4 v0 = *(uint4*)(rp + (sb ^ sw));
    uint4 v1 = *(uint4*)(rp + ((sb + 16) ^ sw));
    char* op = (char*)(o + (mbase + row) * 1024 + h * 64) + sb;
    *(uint4*)op = v0;
    *(uint4*)(op + 16) = v1;
  }
}

// ---------------- launch ----------------
extern "C" void kernel_launch(void* const* d_in, const int* in_sizes, int n_in,
                              void* d_out, int out_size, void* d_ws, size_t ws_size,
                              hipStream_t stream) {
  const float* x     = (const float*)d_in[0];
  const float* w_qkv = (const float*)d_in[1];
  const float* w_out = (const float*)d_in[2];
  const float* b_out = (const float*)d_in[3];
  char* ws = (char*)d_ws;
  const size_t SZ_X  = (size_t)16384 * 1024 * 2;
  const size_t SZ_WQ = (size_t)3072 * 1024 * 2;
  const size_t SZ_WO = (size_t)1024 * 1024 * 2;
  unsigned short* xb  = (unsigned short*)ws;
  unsigned short* wqb = (unsigned short*)(ws + SZ_X);
  unsigned short* wob = (unsigned short*)(ws + SZ_X + SZ_WQ);
  unsigned short* qkv = (unsigned short*)(ws + SZ_X + SZ_WQ + SZ_WO);
  unsigned short* ob  = xb;  // alias: x_bf16 dead after GEMM1

  // one fused convert launch (x + w_qkv + w_out)
  cvt_all<<<2048, 256, 0, stream>>>(x, w_qkv, w_out, xb, wqb, wob);
  // qkv[16384,3072] = xb @ wqb^T   (persistent: 3 tiles/block, GW=6)
  gemm256h<0,0,6,3><<<dim3(256), 512, 0, stream>>>(xb, wqb, qkv, nullptr, 3072, 1024);
  // block-local attention -> ob[16384,1024]
  attn_block<<<dim3(64, 16, 4), 256, 0, stream>>>(qkv, ob);
  // out[16384,1024] = ob @ wob^T + b_out  (fp32; 1 tile/block, GW=4)
  gemm256h<1,1,4,1><<<dim3(256), 512, 0, stream>>>(ob, wob, d_out, b_out, 1024, 1024);
}